// Round 5
// baseline (1451.172 us; speedup 1.0000x reference)
//
#include <hip/hip_runtime.h>

#define N_NODES 100000
#define N_EDGES 3200000
#define IN_F    128
#define EDGE_F  16
#define OUT_F   128
#define K_TOT   144   // IN_F + EDGE_F

#define NBKT 782      // ceil(100000 / 128) node-buckets of 128 nodes
#define BCAP 4800     // per-bucket capacity; lambda ~4092, +11 sigma

typedef float f32x4 __attribute__((ext_vector_type(4)));
typedef int   i32x2 __attribute__((ext_vector_type(2)));

// ---- workspace layout (bytes) ----
// bcnt    : int[782]              @ 0
// bbase   : int[782]              @ 16384
// offsets : int[100001]           @ 400000
// csr2    : int2[3200000]         @ 801040    (25.6 MB: {edge id, row id})
// Se      : float[100000*16]      @ 26401040
// total ~32.8 MB
// buckets : int2[782*4800] (30.0 MB) live in d_out — dead before gather_k
//           writes Sx there.

// Pass A: bucket append. Write frontier = 782 cache lines (one per bucket
// cursor) -> every csr-staging line fills completely while L2-resident,
// unlike a direct 100K-segment scatter whose 25.6 MB frontier thrashes L2.
__global__ void passA_k(const int* __restrict__ col, const int* __restrict__ row,
                        int* __restrict__ bcnt, i32x2* __restrict__ bkt) {
    int e = blockIdx.x * blockDim.x + threadIdx.x;
    if (e < N_EDGES) {
        int c = __builtin_nontemporal_load(col + e);
        int r = __builtin_nontemporal_load(row + e);
        int b = c >> 7;
        int p = atomicAdd(&bcnt[b], 1);
        if (p < BCAP) {                      // memory-safety clamp (never hit)
            i32x2 v; v.x = (e << 7) | (c & 127); v.y = r;   // e < 2^22
            bkt[(size_t)b * BCAP + p] = v;
        }
    }
}

// exclusive scan of the 782 bucket counts (single block)
__global__ void bscan_k(const int* __restrict__ bcnt, int* __restrict__ bbase) {
    __shared__ int s[1024];
    int t = threadIdx.x;
    int v = (t < NBKT) ? min(bcnt[t], BCAP) : 0;
    s[t] = v;
    __syncthreads();
    for (int d = 1; d < 1024; d <<= 1) {
        int u = (t >= d) ? s[t - d] : 0;
        __syncthreads();
        s[t] += u;
        __syncthreads();
    }
    if (t < NBKT) bbase[t] = s[t] - v;
}

// Pass B: one block per bucket. LDS 128-bin histogram + scan -> per-node
// offsets (coalesced write) + csr2 scatter confined to this bucket's
// contiguous ~33 KB region (L2-resident). Second bucket read is an L2 hit.
__global__ __launch_bounds__(256) void passB_k(
        const int* __restrict__ bcnt, const int* __restrict__ bbase,
        const i32x2* __restrict__ bkt, int2* __restrict__ csr2,
        int* __restrict__ offsets) {
    __shared__ int hist[128], cur[128], scn[128];
    int b = blockIdx.x, t = threadIdx.x;
    int cnt  = min(bcnt[b], BCAP);
    int base = bbase[b];
    if (t < 128) hist[t] = 0;
    __syncthreads();
    const i32x2* mybkt = bkt + (size_t)b * BCAP;
    for (int i = t; i < cnt; i += 256)
        atomicAdd(&hist[mybkt[i].x & 127], 1);
    __syncthreads();
    if (t < 128) scn[t] = hist[t];
    __syncthreads();
    for (int d = 1; d < 128; d <<= 1) {
        int u = 0;
        if (t < 128 && t >= d) u = scn[t - d];
        __syncthreads();
        if (t < 128) scn[t] += u;
        __syncthreads();
    }
    if (t < 128) {
        int excl = scn[t] - hist[t];
        cur[t] = excl;
        int n = b * 128 + t;
        if (n < N_NODES) offsets[n] = base + excl;
    }
    if (b == 0 && t == 0) offsets[N_NODES] = N_EDGES;
    __syncthreads();
    for (int i = t; i < cnt; i += 256) {
        i32x2 v = mybkt[i];
        int p = atomicAdd(&cur[v.x & 127], 1);        // LDS atomic: fast
        csr2[base + p] = make_int2(v.x >> 7, v.y);    // {edge id, row id}
    }
}

// One wave per node. csr2 gives {e, row} in one coalesced NT 8B load.
// x rows: float4, two rows per wave-instruction (lane halves), 8 pair-loads
// deep -> 16 rows in flight; x loads are TEMPORAL (we want the reuse in L2).
// Read-once streams (csr2, ea) and write-once streams (Sx, Se) are NT.
__global__ __launch_bounds__(256) void gather_k(
        const float* __restrict__ x, const float* __restrict__ ea,
        const int* __restrict__ offsets, const int* __restrict__ csr2,
        float* __restrict__ Sx, float* __restrict__ Se) {
    const int wave = threadIdx.x >> 6;
    const int lane = threadIdx.x & 63;
    const int n = blockIdx.x * 4 + wave;   // 25000 blocks * 4 waves = 100000

    const int off0 = offsets[n];
    const int deg  = offsets[n + 1] - off0;

    const int half = lane >> 5;   // x: which row of the pair
    const int l31  = lane & 31;   // x: float4 slot within row
    const int eg16 = lane >> 2;   // ea: edge within 16-group
    const int l3   = lane & 3;    // ea: float4 slot within row

    f32x4 ax = {0.f, 0.f, 0.f, 0.f};
    f32x4 se = {0.f, 0.f, 0.f, 0.f};

    for (int base = 0; base < deg; base += 64) {
        int m = deg - base; if (m > 64) m = 64;
        int e = 0, r = 0;
        if (lane < m) {
            i32x2 er = __builtin_nontemporal_load(
                ((const i32x2*)csr2) + off0 + base + lane);   // coalesced
            e = er.x; r = er.y;
        }
        int j = 0;
        for (; j + 16 <= m; j += 16) {
            int r0 = __shfl(r, j + 0  + half);
            int r1 = __shfl(r, j + 2  + half);
            int r2 = __shfl(r, j + 4  + half);
            int r3 = __shfl(r, j + 6  + half);
            int r4 = __shfl(r, j + 8  + half);
            int r5 = __shfl(r, j + 10 + half);
            int r6 = __shfl(r, j + 12 + half);
            int r7 = __shfl(r, j + 14 + half);
            int ej = __shfl(e, j + eg16);
            f32x4 v0 = ((const f32x4*)(x + (size_t)r0 * IN_F))[l31];
            f32x4 v1 = ((const f32x4*)(x + (size_t)r1 * IN_F))[l31];
            f32x4 v2 = ((const f32x4*)(x + (size_t)r2 * IN_F))[l31];
            f32x4 v3 = ((const f32x4*)(x + (size_t)r3 * IN_F))[l31];
            f32x4 v4 = ((const f32x4*)(x + (size_t)r4 * IN_F))[l31];
            f32x4 v5 = ((const f32x4*)(x + (size_t)r5 * IN_F))[l31];
            f32x4 v6 = ((const f32x4*)(x + (size_t)r6 * IN_F))[l31];
            f32x4 v7 = ((const f32x4*)(x + (size_t)r7 * IN_F))[l31];
            f32x4 w  = __builtin_nontemporal_load(
                ((const f32x4*)ea) + (size_t)ej * 4 + l3);
            ax += (v0 + v1) + (v2 + v3) + (v4 + v5) + (v6 + v7);
            se += w;
        }
        // tail: 2 x-rows per step (lane halves), 2 ea rows on lanes 0..7
        for (; j < m; j += 2) {
            int rj = __shfl(r, j + half);
            if (j + half < m) {
                f32x4 v = ((const f32x4*)(x + (size_t)rj * IN_F))[l31];
                ax += v;
            }
            int eg = eg16 & 1;
            int ej = __shfl(e, j + eg);
            if (lane < 8 && (j + eg) < m) {
                f32x4 w = __builtin_nontemporal_load(
                    ((const f32x4*)ea) + (size_t)ej * 4 + l3);
                se += w;
            }
        }
    }

    // combine the two row-parity halves for x
    ax.x += __shfl_xor(ax.x, 32);
    ax.y += __shfl_xor(ax.y, 32);
    ax.z += __shfl_xor(ax.z, 32);
    ax.w += __shfl_xor(ax.w, 32);
    // reduce se across the 16 edge-groups (lanes with same lane&3)
    #pragma unroll
    for (int off = 4; off < 64; off <<= 1) {
        se.x += __shfl_xor(se.x, off);
        se.y += __shfl_xor(se.y, off);
        se.z += __shfl_xor(se.z, off);
        se.w += __shfl_xor(se.w, off);
    }
    if (lane < 32)
        __builtin_nontemporal_store(ax, ((f32x4*)(Sx + (size_t)n * IN_F)) + l31);
    if (lane < 4)
        __builtin_nontemporal_store(se, ((f32x4*)(Se + (size_t)n * EDGE_F)) + l3);
}

// [100000 x 144] @ [144 x 128]^T GEMM with per-node deg*b bias and /deg.
// Block: 256 thr = (to 0..31: 4 outputs) x (tn 0..7: 8 nodes). Tile = 64 nodes
// (halves W re-staging and per-node LDS traffic vs TILE_N=32). In-place on
// d_out: block stages its own S rows to LDS before overwriting them.
#define TILE_N 64
__global__ __launch_bounds__(256) void gemm_k(
        const float* __restrict__ Sx, const float* __restrict__ Se,
        const int* __restrict__ offsets, const float* __restrict__ W,
        const float* __restrict__ b, float* __restrict__ out) {
    __shared__ float Wt[72 * 132];   // half of W, transposed [k][o], padded row 132
    __shared__ float Sl[144 * 68];   // S tile transposed [k][n], padded row 68

    int tid = threadIdx.x;
    int to4 = (tid & 31) * 4;
    int tn8 = (tid >> 5) * 8;
    int n0 = blockIdx.x * TILE_N;

    // stage Sx rows (coalesced read, transposed LDS write); read-once -> NT
    for (int idx = tid; idx < TILE_N * IN_F; idx += 256) {
        int n = idx >> 7, k = idx & 127;
        int nn = n0 + n;
        Sl[k * 68 + n] = (nn < N_NODES)
            ? __builtin_nontemporal_load(Sx + (size_t)nn * IN_F + k) : 0.f;
    }
    // stage Se rows
    for (int idx = tid; idx < TILE_N * EDGE_F; idx += 256) {
        int n = idx >> 4, k = idx & 15;
        int nn = n0 + n;
        Sl[(IN_F + k) * 68 + n] = (nn < N_NODES)
            ? __builtin_nontemporal_load(Se + (size_t)nn * EDGE_F + k) : 0.f;
    }

    f32x4 a0 = {0,0,0,0}, a1 = {0,0,0,0}, a2 = {0,0,0,0}, a3 = {0,0,0,0};
    f32x4 a4 = {0,0,0,0}, a5 = {0,0,0,0}, a6 = {0,0,0,0}, a7 = {0,0,0,0};

    for (int half = 0; half < 2; ++half) {
        __syncthreads();   // S staged (half 0) / prev half compute done
        int kbase = half * 72;
        for (int idx = tid; idx < 72 * 128; idx += 256) {
            int o = idx / 72, kl = idx % 72;          // coalesced W read
            Wt[kl * 132 + o] = W[(size_t)o * K_TOT + kbase + kl];
        }
        __syncthreads();

        #pragma unroll 4
        for (int kl = 0; kl < 72; ++kl) {
            f32x4 w4 = *(const f32x4*)&Wt[kl * 132 + to4];
            f32x4 s0 = *(const f32x4*)&Sl[(kbase + kl) * 68 + tn8];
            f32x4 s1 = *(const f32x4*)&Sl[(kbase + kl) * 68 + tn8 + 4];
            a0 += s0.x * w4; a1 += s0.y * w4; a2 += s0.z * w4; a3 += s0.w * w4;
            a4 += s1.x * w4; a5 += s1.y * w4; a6 += s1.z * w4; a7 += s1.w * w4;
        }
    }

    f32x4 b4 = *(const f32x4*)&b[to4];
    f32x4 accs[8] = {a0, a1, a2, a3, a4, a5, a6, a7};
    #pragma unroll
    for (int j = 0; j < 8; ++j) {
        int n = n0 + tn8 + j;
        if (n < N_NODES) {
            float fdeg = (float)(offsets[n + 1] - offsets[n]);
            float inv = 1.0f / fmaxf(fdeg, 1.0f);
            f32x4 o4 = (accs[j] + fdeg * b4) * inv;
            __builtin_nontemporal_store(o4, (f32x4*)(out + (size_t)n * OUT_F + to4));
        }
    }
}

extern "C" void kernel_launch(void* const* d_in, const int* in_sizes, int n_in,
                              void* d_out, int out_size, void* d_ws, size_t ws_size,
                              hipStream_t stream) {
    const float* x  = (const float*)d_in[0];
    const int*   ei = (const int*)d_in[1];     // int32 per harness convention
    const float* ea = (const float*)d_in[2];
    const float* W  = (const float*)d_in[3];
    const float* b  = (const float*)d_in[4];
    float* out = (float*)d_out;

    char* ws = (char*)d_ws;
    int*   bcnt    = (int*)(ws + 0);
    int*   bbase   = (int*)(ws + 16384);
    int*   offsets = (int*)(ws + 400000);
    int2*  csr2    = (int2*)(ws + 801040);
    float* Se      = (float*)(ws + 26401040);
    i32x2* bkt     = (i32x2*)d_out;            // 30.0 MB; dead before gather_k

    const int* row = ei;             // edge_index[0]
    const int* col = ei + N_EDGES;   // edge_index[1]

    hipMemsetAsync(bcnt, 0, NBKT * sizeof(int), stream);
    passA_k<<<(N_EDGES + 255) / 256, 256, 0, stream>>>(col, row, bcnt, bkt);
    bscan_k<<<1, 1024, 0, stream>>>(bcnt, bbase);
    passB_k<<<NBKT, 256, 0, stream>>>(bcnt, bbase, bkt, csr2, offsets);
    gather_k<<<N_NODES / 4, 256, 0, stream>>>(x, ea, offsets, (const int*)csr2, out, Se);
    gemm_k<<<(N_NODES + TILE_N - 1) / TILE_N, 256, 0, stream>>>(out, Se, offsets, W, b, out);
}